// Round 2
// baseline (968.091 us; speedup 1.0000x reference)
//
#include <hip/hip_runtime.h>

// 3x3 stride-1 pad-1 conv, NCHW fp32 in/out, per-tap MFMA f16.
// B=8, CIN=COUT=16, H=W=1024.
//
// v3: occupancy push. TILE 8 rows x 64 px per block (v2: 16x64).
//  - LDS pad removed (CPAD 20 -> 16 halfs/px); read bank conflicts avoided
//    via XOR swizzle of the 8B-unit index: su = (c>>2) ^ ((px>>2)&3).
//    A-frag ds_read_b64 provably conflict-free (16 consecutive px -> 16
//    distinct 8B units mod 16). Staging f16x2 writes pick up a small 4-way
//    conflict (negligible: ~tens of cycles/wave).
//  - LDS 47.6 KB -> 21.1 KB  =>  3 -> 7 blocks/CU (12 -> 28 waves/CU).
//  - halo ratio 18/16 -> 10/8; L2 absorbs most vertical halo re-reads
//    (measured in v2: fetch 1.02x ideal).
//
// MFMA 16x16x16 f16 mapping (verified v1):
//   A[m=lane&15][k=4*(lane>>4)+j]   m = pixel-in-tile, k = cin
//   B[k][n=lane&15]                 n = cout
//   D[row=m=4*(lane>>4)+reg][col=n=lane&15] -> float4 store, cout=ln

typedef _Float16 f16x4 __attribute__((ext_vector_type(4)));
typedef _Float16 f16x2 __attribute__((ext_vector_type(2)));
typedef float f32x4 __attribute__((ext_vector_type(4)));

#define B_N    8
#define C_IN   16
#define C_OUT  16
#define H_N    1024
#define W_N    1024
#define TILE_W 64
#define TILE_H 8
#define LDS_R  (TILE_H + 2)   // 10 staged rows
#define LDS_W  (TILE_W + 2)   // 66 staged cols

__global__ __launch_bounds__(256, 6) void conv3x3_mfma(
    const float* __restrict__ x, const float* __restrict__ wt,
    float* __restrict__ out)
{
    // flat [10][66][16] halfs, 8B units XOR-swizzled within each pixel row
    __shared__ _Float16 s_x[LDS_R * LDS_W * 16];

    const int w0   = blockIdx.x * TILE_W;   // 0..960
    const int h0   = blockIdx.y * TILE_H;   // 0..1016
    const int b    = blockIdx.z;
    const int tid  = threadIdx.x;
    const int lane = tid & 63;
    const int q    = lane >> 4;             // 0..3
    const int ln   = lane & 15;             // 0..15
    const int wave = tid >> 6;              // 0..3
    const int seg  = wave * 16;             // wave's 16-pixel segment

    // ---- stage interior: 10 rows x 8 cin-pairs x 16 float4 = 1280 = 5*256
    // flat bits: [3:0]=i4  [6:4]=cp  [10:7]=r   (shifts only)
#pragma unroll
    for (int it = 0; it < 5; ++it) {
        const int flat = tid + 256 * it;
        const int i4 = flat & 15;
        const int cp = (flat >> 4) & 7;
        const int r  = flat >> 7;           // 0..9
        const int gh = h0 - 1 + r;
        const int gw = w0 + 4 * i4;
        f32x4 va = {0.f, 0.f, 0.f, 0.f};
        f32x4 vb = {0.f, 0.f, 0.f, 0.f};
        if ((unsigned)gh < (unsigned)H_N) {
            const size_t base =
                (((size_t)b * C_IN + 2 * cp) * H_N + gh) * W_N + gw;
            va = *(const f32x4*)&x[base];
            vb = *(const f32x4*)&x[base + (size_t)H_N * W_N];
        }
#pragma unroll
        for (int j = 0; j < 4; ++j) {
            const int px = 1 + 4 * i4 + j;
            const int su = (cp >> 1) ^ ((px >> 2) & 3);
            f16x2 p;
            p[0] = (_Float16)va[j];
            p[1] = (_Float16)vb[j];
            *(f16x2*)&s_x[(r * LDS_W + px) * 16 + su * 4 + 2 * (cp & 1)] = p;
        }
    }

    // ---- stage halo columns: 10 rows x 8 cin-pairs x 2 sides = 160 ----
    if (tid < 160) {
        const int side = tid & 1;
        const int cp   = (tid >> 1) & 7;
        const int r    = tid >> 4;          // 0..9
        const int px   = side ? (LDS_W - 1) : 0;   // 0 or 65
        const int gw   = w0 - 1 + px;
        const int gh   = h0 - 1 + r;
        float a = 0.f, c2 = 0.f;
        if ((unsigned)gh < (unsigned)H_N && (unsigned)gw < (unsigned)W_N) {
            const size_t base =
                (((size_t)b * C_IN + 2 * cp) * H_N + gh) * W_N + gw;
            a  = x[base];
            c2 = x[base + (size_t)H_N * W_N];
        }
        const int su = (cp >> 1) ^ ((px >> 2) & 3);
        f16x2 p;
        p[0] = (_Float16)a;
        p[1] = (_Float16)c2;
        *(f16x2*)&s_x[(r * LDS_W + px) * 16 + su * 4 + 2 * (cp & 1)] = p;
    }

    // ---- B fragments: 9 taps, in registers (overlaps staging latency) ----
    f16x4 bfrag[9];
#pragma unroll
    for (int kh = 0; kh < 3; ++kh) {
#pragma unroll
        for (int kw = 0; kw < 3; ++kw) {
            f16x4 f;
#pragma unroll
            for (int j = 0; j < 4; ++j) {
                const int cin = 4 * q + j;
                f[j] = (_Float16)wt[((ln * C_IN + cin) * 3 + kh) * 3 + kw];
            }
            bfrag[kh * 3 + kw] = f;
        }
    }

    __syncthreads();

    // ---- compute: walk 10 staged rows once; 3 rotating accumulators ----
    // staged row ir feeds output rows r = ir (kh=0), ir-1 (kh=1), ir-2 (kh=2)
    // Full unroll -> all acc[] indices compile-time.
    f32x4 acc[3];
    const size_t outbase = ((size_t)b * C_OUT + ln) * H_N;
#pragma unroll
    for (int ir = 0; ir < LDS_R; ++ir) {
        const int pxb = seg + ln;
        const int sw0 = (q ^ (((pxb + 0) >> 2) & 3)) << 2;
        const int sw1 = (q ^ (((pxb + 1) >> 2) & 3)) << 2;
        const int sw2 = (q ^ (((pxb + 2) >> 2) & 3)) << 2;
        const f16x4 a0 = *(const f16x4*)&s_x[(ir * LDS_W + pxb + 0) * 16 + sw0];
        const f16x4 a1 = *(const f16x4*)&s_x[(ir * LDS_W + pxb + 1) * 16 + sw1];
        const f16x4 a2 = *(const f16x4*)&s_x[(ir * LDS_W + pxb + 2) * 16 + sw2];

        if (ir <= TILE_H - 1) {            // kh=0: open row r=ir
            f32x4 t = {0.f, 0.f, 0.f, 0.f};
            t = __builtin_amdgcn_mfma_f32_16x16x16f16(a0, bfrag[0], t, 0, 0, 0);
            t = __builtin_amdgcn_mfma_f32_16x16x16f16(a1, bfrag[1], t, 0, 0, 0);
            t = __builtin_amdgcn_mfma_f32_16x16x16f16(a2, bfrag[2], t, 0, 0, 0);
            acc[ir % 3] = t;
        }
        if (ir >= 1 && ir - 1 <= TILE_H - 1) {   // kh=1: row r=ir-1
            f32x4 t = acc[(ir - 1) % 3];
            t = __builtin_amdgcn_mfma_f32_16x16x16f16(a0, bfrag[3], t, 0, 0, 0);
            t = __builtin_amdgcn_mfma_f32_16x16x16f16(a1, bfrag[4], t, 0, 0, 0);
            t = __builtin_amdgcn_mfma_f32_16x16x16f16(a2, bfrag[5], t, 0, 0, 0);
            acc[(ir - 1) % 3] = t;
        }
        if (ir >= 2) {                     // kh=2: close row r=ir-2, store
            const int r = ir - 2;
            f32x4 t = acc[r % 3];
            t = __builtin_amdgcn_mfma_f32_16x16x16f16(a0, bfrag[6], t, 0, 0, 0);
            t = __builtin_amdgcn_mfma_f32_16x16x16f16(a1, bfrag[7], t, 0, 0, 0);
            t = __builtin_amdgcn_mfma_f32_16x16x16f16(a2, bfrag[8], t, 0, 0, 0);
            const int wout = w0 + seg + 4 * q;
            *(f32x4*)&out[(outbase + (h0 + r)) * W_N + wout] = t;
        }
    }
}

extern "C" void kernel_launch(void* const* d_in, const int* in_sizes, int n_in,
                              void* d_out, int out_size, void* d_ws, size_t ws_size,
                              hipStream_t stream) {
    const float* x  = (const float*)d_in[0];
    const float* wt = (const float*)d_in[1];
    float* out = (float*)d_out;
    dim3 grid(W_N / TILE_W, H_N / TILE_H, B_N);
    conv3x3_mfma<<<grid, 256, 0, stream>>>(x, wt, out);
}